// Round 1
// baseline (1387.432 us; speedup 1.0000x reference)
//
#include <hip/hip_runtime.h>
#include <math.h>

// Problem dims
#define T_DIM 3
#define B_DIM 2048
#define NIMG  (T_DIM * B_DIM)   // 6144

// ---------------------------------------------------------------------------
// Generic conv 4x4 stride2 pad1 + ReLU over LDS tensors (unpadded [C][H][W]).
// Thread tid handles COB consecutive output channels for NIT positions.
// Lane mapping: task = tid + k*256; cg = task % NCG (channel group), so
// adjacent lanes share spatial rows -> LDS reads broadcast within cg groups.
// Weights register-cached per (ci, co-group): float4 loads, wave-broadcast.
// ---------------------------------------------------------------------------
template<int CIN, int COUT, int IH, int OH, int COB, int NIT>
__device__ __forceinline__ void convtile(const float* __restrict__ gw,
                                         const float* __restrict__ gb,
                                         const float* __restrict__ sin_,
                                         float* __restrict__ sout,
                                         int tid)
{
    constexpr int NCG   = COUT / COB;
    constexpr int P     = OH * OH;
    constexpr int TASKS = P * NCG;
    if (TASKS < 256) { if (tid >= TASKS) return; }

    const int co0 = (tid % NCG) * COB;
    int ohv[NIT], owv[NIT];
#pragma unroll
    for (int k = 0; k < NIT; k++) {
        int pos = (tid + k * 256) / NCG;
        ohv[k] = pos / OH;
        owv[k] = pos % OH;
    }

    float acc[COB][NIT];
#pragma unroll
    for (int j = 0; j < COB; j++) {
        float bv = gb[co0 + j];
#pragma unroll
        for (int k = 0; k < NIT; k++) acc[j][k] = bv;
    }

    for (int ci = 0; ci < CIN; ci++) {
        float wreg[COB][16];
#pragma unroll
        for (int j = 0; j < COB; j++) {
            const float4* wp = (const float4*)(gw + ((co0 + j) * CIN + ci) * 16);
#pragma unroll
            for (int q = 0; q < 4; q++) {
                float4 w4 = wp[q];
                wreg[j][q * 4 + 0] = w4.x;
                wreg[j][q * 4 + 1] = w4.y;
                wreg[j][q * 4 + 2] = w4.z;
                wreg[j][q * 4 + 3] = w4.w;
            }
        }
        const float* ipc = sin_ + ci * IH * IH;
#pragma unroll
        for (int k = 0; k < NIT; k++) {
            const int oh = ohv[k], ow = owv[k];
#pragma unroll
            for (int kh = 0; kh < 4; kh++) {
                const int ih = 2 * oh - 1 + kh;
                if ((unsigned)ih < (unsigned)IH) {
                    const float* rp = ipc + ih * IH;
#pragma unroll
                    for (int kw = 0; kw < 4; kw++) {
                        const int iw = 2 * ow - 1 + kw;
                        if ((unsigned)iw < (unsigned)IH) {
                            const float xv = rp[iw];
#pragma unroll
                            for (int j = 0; j < COB; j++)
                                acc[j][k] = fmaf(xv, wreg[j][kh * 4 + kw], acc[j][k]);
                        }
                    }
                }
            }
        }
    }
#pragma unroll
    for (int j = 0; j < COB; j++) {
#pragma unroll
        for (int k = 0; k < NIT; k++) {
            int pos = (tid + k * 256) / NCG;
            sout[(co0 + j) * P + pos] = fmaxf(acc[j][k], 0.f);
        }
    }
}

// ---------------------------------------------------------------------------
// Kernel 1: conv layers 0..3, one block per image. LDS = exactly 64 KB.
//   sA: image 3x64x64 (12288 f), reused for l1 out 8x16x16 (2048 f)
//   sB: l0 out 4x32x32 (4096 f), reused for l2 out 16x8x8 (1024 f)
//   l3 out 32x4x4 -> global ws [img][512]
// ---------------------------------------------------------------------------
__global__ __launch_bounds__(256) void conv03_kernel(
    const float* __restrict__ img,
    const float* __restrict__ w0, const float* __restrict__ b0,
    const float* __restrict__ w1, const float* __restrict__ b1,
    const float* __restrict__ w2, const float* __restrict__ b2,
    const float* __restrict__ w3, const float* __restrict__ b3,
    float* __restrict__ l3out)
{
    __shared__ float sA[12288];
    __shared__ float sB[4096];
    const int tid  = threadIdx.x;
    const int gimg = blockIdx.x;          // t*2048 + b
    const int t    = gimg >> 11;

    // stage image (coalesced float4)
    {
        const float4* ip4 = (const float4*)(img + (size_t)gimg * 12288);
        float4* sA4 = (float4*)sA;
        for (int i = tid; i < 3072; i += 256) sA4[i] = ip4[i];
    }
    __syncthreads();
    convtile<3, 4, 64, 32, 4, 4>(w0 + t * 192,  b0 + t * 4,  sA, sB, tid);
    __syncthreads();
    convtile<4, 8, 32, 16, 4, 2>(w1 + t * 512,  b1 + t * 8,  sB, sA, tid);
    __syncthreads();
    convtile<8, 16, 16, 8, 4, 1>(w2 + t * 2048, b2 + t * 16, sA, sB, tid);
    __syncthreads();
    convtile<16, 32, 8, 4, 4, 1>(w3 + t * 8192, b3 + t * 32, sB,
                                 l3out + (size_t)gimg * 512, tid);
}

// ---------------------------------------------------------------------------
// Kernel 2: conv layers 4..5, 16 images per block (amortizes the 640 KB of
// l4+l5 weights across 16 images). LDS padded pitches (516/260) break the
// 2048-float image-stride bank aliasing.
// ---------------------------------------------------------------------------
__global__ __launch_bounds__(256) void conv45_kernel(
    const float* __restrict__ l3out,
    const float* __restrict__ w4g, const float* __restrict__ b4g,
    const float* __restrict__ w5g, const float* __restrict__ b5g,
    float* __restrict__ feats)
{
    __shared__ float sIn[16 * 516];
    __shared__ float sMid[16 * 260];
    const int tid  = threadIdx.x;
    const int img0 = blockIdx.x << 4;
    const int t    = img0 >> 11;

    // stage l3 outputs
    {
        const float4* gp = (const float4*)(l3out + (size_t)img0 * 512);
        for (int i = tid; i < 2048; i += 256) {
            int im = i >> 7;       // image index (128 float4 per image)
            int d4 = i & 127;
            *(float4*)&sIn[im * 516 + d4 * 4] = gp[i];
        }
    }
    __syncthreads();

    // ---- layer 4: [32,4,4] -> [64,2,2], thread = 4 co x 1 pos x 4 images
    {
        const int ig  = (tid & 3) << 2;       // image base within block
        const int p   = (tid >> 2) & 3;       // output position
        const int co0 = (tid >> 4) << 2;      // 0..60
        const int oh = p >> 1, ow = p & 1;
        const float* wt = w4g + t * 32768;
        float acc[4][4];
#pragma unroll
        for (int j = 0; j < 4; j++) {
            float bv = b4g[t * 64 + co0 + j];
#pragma unroll
            for (int m = 0; m < 4; m++) acc[j][m] = bv;
        }
        for (int ci = 0; ci < 32; ci++) {
            float wreg[4][16];
#pragma unroll
            for (int j = 0; j < 4; j++) {
                const float4* wp = (const float4*)(wt + ((co0 + j) * 32 + ci) * 16);
#pragma unroll
                for (int q = 0; q < 4; q++) {
                    float4 w4 = wp[q];
                    wreg[j][q * 4 + 0] = w4.x;
                    wreg[j][q * 4 + 1] = w4.y;
                    wreg[j][q * 4 + 2] = w4.z;
                    wreg[j][q * 4 + 3] = w4.w;
                }
            }
#pragma unroll
            for (int kh = 0; kh < 4; kh++) {
                int ih = 2 * oh - 1 + kh;
                if ((unsigned)ih < 4u) {
#pragma unroll
                    for (int kw = 0; kw < 4; kw++) {
                        int iw = 2 * ow - 1 + kw;
                        if ((unsigned)iw < 4u) {
                            float xv[4];
#pragma unroll
                            for (int m = 0; m < 4; m++)
                                xv[m] = sIn[(ig + m) * 516 + ci * 16 + ih * 4 + iw];
#pragma unroll
                            for (int j = 0; j < 4; j++)
#pragma unroll
                                for (int m = 0; m < 4; m++)
                                    acc[j][m] = fmaf(xv[m], wreg[j][kh * 4 + kw], acc[j][m]);
                        }
                    }
                }
            }
        }
#pragma unroll
        for (int j = 0; j < 4; j++)
#pragma unroll
            for (int m = 0; m < 4; m++)
                sMid[(ig + m) * 260 + (co0 + j) * 4 + p] = fmaxf(acc[j][m], 0.f);
    }
    __syncthreads();

    // ---- layer 5: [64,2,2] -> [128] (only kernel taps (1..2,1..2) valid)
    {
        const int ig  = (tid & 3) << 2;
        const int co0 = (tid >> 2) << 1;      // 0..126
        const float* wt = w5g + t * 131072;
        float acc[2][4];
#pragma unroll
        for (int j = 0; j < 2; j++) {
            float bv = b5g[t * 128 + co0 + j];
#pragma unroll
            for (int m = 0; m < 4; m++) acc[j][m] = bv;
        }
        for (int ci = 0; ci < 64; ci++) {
            float wreg[2][4];
#pragma unroll
            for (int j = 0; j < 2; j++) {
                const float* wp = wt + ((co0 + j) * 64 + ci) * 16;
                wreg[j][0] = wp[5];  wreg[j][1] = wp[6];
                wreg[j][2] = wp[9];  wreg[j][3] = wp[10];
            }
#pragma unroll
            for (int q = 0; q < 4; q++) {
#pragma unroll
                for (int m = 0; m < 4; m++) {
                    float xv = sMid[(ig + m) * 260 + ci * 4 + q];
#pragma unroll
                    for (int j = 0; j < 2; j++)
                        acc[j][m] = fmaf(xv, wreg[j][q], acc[j][m]);
                }
            }
        }
#pragma unroll
        for (int j = 0; j < 2; j++)
#pragma unroll
            for (int m = 0; m < 4; m++)
                feats[(size_t)(img0 + ig + m) * 128 + co0 + j] = fmaxf(acc[j][m], 0.f);
    }
}

// ---------------------------------------------------------------------------
// Kernel 3: MLP 128->32->32->64, LSTM(H=20) over T=3, 20 heads 20->32->32->1.
// One 64-lane wave per batch element. t-loop folded inside each dot so head
// weights are read once per block, not 3x.
// ---------------------------------------------------------------------------
__device__ __forceinline__ float sigmoidf_(float x) { return 1.f / (1.f + expf(-x)); }

__global__ __launch_bounds__(64) void head_kernel(
    const float* __restrict__ feats,
    const float* __restrict__ mw1, const float* __restrict__ mb1,
    const float* __restrict__ mw2, const float* __restrict__ mb2,
    const float* __restrict__ mw3, const float* __restrict__ mb3,
    const float* __restrict__ wih, const float* __restrict__ whh,
    const float* __restrict__ bih, const float* __restrict__ bhh,
    const float* __restrict__ hw1, const float* __restrict__ hb1,
    const float* __restrict__ hw2, const float* __restrict__ hb2,
    const float* __restrict__ hw3, const float* __restrict__ hb3,
    float* __restrict__ out)
{
    const int b   = blockIdx.x;
    const int tid = threadIdx.x;
    __shared__ float sX[384];        // feats [3][128]
    __shared__ float sH1[96];        // [3][32]
    __shared__ float sH2[96];
    __shared__ float sF[192];        // [3][64]
    __shared__ float sGates[80];
    __shared__ float sHs[20], sCs[20], sHseq[60];
    __shared__ float sA1[3 * 640];   // [3][20][32]
    __shared__ float sA2[3 * 640];

    // load features for this b (coalesced float4 within rows)
    for (int i = tid; i < 96; i += 64) {
        int t = i >> 5, d4 = i & 31;
        ((float4*)sX)[i] = ((const float4*)(feats + (size_t)(t * 2048 + b) * 128))[d4];
    }
    __syncthreads();

    // MLP layer1: 128 -> 32 (lanes 0..31, all 3 t at once)
    if (tid < 32) {
        const float4* wr = (const float4*)(mw1 + tid * 128);
        float a0 = mb1[tid], a1 = a0, a2 = a0;
        for (int d4 = 0; d4 < 32; d4++) {
            float4 w  = wr[d4];
            float4 x0 = ((const float4*)sX)[d4];
            float4 x1 = ((const float4*)sX)[32 + d4];
            float4 x2 = ((const float4*)sX)[64 + d4];
            a0 = fmaf(w.x, x0.x, a0); a0 = fmaf(w.y, x0.y, a0);
            a0 = fmaf(w.z, x0.z, a0); a0 = fmaf(w.w, x0.w, a0);
            a1 = fmaf(w.x, x1.x, a1); a1 = fmaf(w.y, x1.y, a1);
            a1 = fmaf(w.z, x1.z, a1); a1 = fmaf(w.w, x1.w, a1);
            a2 = fmaf(w.x, x2.x, a2); a2 = fmaf(w.y, x2.y, a2);
            a2 = fmaf(w.z, x2.z, a2); a2 = fmaf(w.w, x2.w, a2);
        }
        sH1[tid] = fmaxf(a0, 0.f); sH1[32 + tid] = fmaxf(a1, 0.f); sH1[64 + tid] = fmaxf(a2, 0.f);
    }
    __syncthreads();

    // MLP layer2: 32 -> 32
    if (tid < 32) {
        const float* wr = mw2 + tid * 32;
        float a0 = mb2[tid], a1 = a0, a2 = a0;
#pragma unroll
        for (int d = 0; d < 32; d++) {
            float w = wr[d];
            a0 = fmaf(w, sH1[d], a0);
            a1 = fmaf(w, sH1[32 + d], a1);
            a2 = fmaf(w, sH1[64 + d], a2);
        }
        sH2[tid] = fmaxf(a0, 0.f); sH2[32 + tid] = fmaxf(a1, 0.f); sH2[64 + tid] = fmaxf(a2, 0.f);
    }
    __syncthreads();

    // MLP layer3: 32 -> 64 (no relu)
    {
        const float* wr = mw3 + tid * 32;
        float a0 = mb3[tid], a1 = a0, a2 = a0;
#pragma unroll
        for (int d = 0; d < 32; d++) {
            float w = wr[d];
            a0 = fmaf(w, sH2[d], a0);
            a1 = fmaf(w, sH2[32 + d], a1);
            a2 = fmaf(w, sH2[64 + d], a2);
        }
        sF[tid] = a0; sF[64 + tid] = a1; sF[128 + tid] = a2;
    }
    if (tid < 20) { sHs[tid] = 0.f; sCs[tid] = 0.f; }
    __syncthreads();

    // LSTM over T=3 (torch gate order i,f,g,o)
    for (int t = 0; t < 3; t++) {
        for (int i = tid; i < 80; i += 64) {
            float a = bih[i] + bhh[i];
            const float4* wi = (const float4*)(wih + i * 64);
            const float4* xr = (const float4*)(sF + t * 64);
#pragma unroll
            for (int d4 = 0; d4 < 16; d4++) {
                float4 w = wi[d4]; float4 x = xr[d4];
                a = fmaf(w.x, x.x, a); a = fmaf(w.y, x.y, a);
                a = fmaf(w.z, x.z, a); a = fmaf(w.w, x.w, a);
            }
            const float* wh = whh + i * 20;
#pragma unroll
            for (int d = 0; d < 20; d++) a = fmaf(wh[d], sHs[d], a);
            sGates[i] = a;
        }
        __syncthreads();
        if (tid < 20) {
            float ig = sigmoidf_(sGates[tid]);
            float fg = sigmoidf_(sGates[20 + tid]);
            float g  = tanhf(sGates[40 + tid]);
            float og = sigmoidf_(sGates[60 + tid]);
            float c  = fg * sCs[tid] + ig * g;
            sCs[tid] = c;
            float h = og * tanhf(c);
            sHs[tid] = h;
            sHseq[t * 20 + tid] = h;
        }
        __syncthreads();
    }

    // Heads layer1: 20 -> 32 for 20 heads, all 3 t per weight read
    for (int i = tid; i < 640; i += 64) {
        float wrow[20];
        const float4* wr = (const float4*)(hw1 + i * 20);
#pragma unroll
        for (int q = 0; q < 5; q++) {
            float4 w = wr[q];
            wrow[q * 4 + 0] = w.x; wrow[q * 4 + 1] = w.y;
            wrow[q * 4 + 2] = w.z; wrow[q * 4 + 3] = w.w;
        }
        float bv = hb1[i];
        float a0 = bv, a1 = bv, a2 = bv;
#pragma unroll
        for (int d = 0; d < 20; d++) {
            float w = wrow[d];
            a0 = fmaf(w, sHseq[d], a0);
            a1 = fmaf(w, sHseq[20 + d], a1);
            a2 = fmaf(w, sHseq[40 + d], a2);
        }
        sA1[i] = fmaxf(a0, 0.f); sA1[640 + i] = fmaxf(a1, 0.f); sA1[1280 + i] = fmaxf(a2, 0.f);
    }
    __syncthreads();

    // Heads layer2: 32 -> 32
    for (int i = tid; i < 640; i += 64) {
        int k = i >> 5;
        float wrow[32];
        const float4* wr = (const float4*)(hw2 + i * 32);
#pragma unroll
        for (int q = 0; q < 8; q++) {
            float4 w = wr[q];
            wrow[q * 4 + 0] = w.x; wrow[q * 4 + 1] = w.y;
            wrow[q * 4 + 2] = w.z; wrow[q * 4 + 3] = w.w;
        }
        float bv = hb2[i];
        float a0 = bv, a1 = bv, a2 = bv;
#pragma unroll
        for (int d = 0; d < 32; d++) {
            float w = wrow[d];
            a0 = fmaf(w, sA1[k * 32 + d], a0);
            a1 = fmaf(w, sA1[640 + k * 32 + d], a1);
            a2 = fmaf(w, sA1[1280 + k * 32 + d], a2);
        }
        sA2[i] = fmaxf(a0, 0.f); sA2[640 + i] = fmaxf(a1, 0.f); sA2[1280 + i] = fmaxf(a2, 0.f);
    }
    __syncthreads();

    // Heads layer3: 32 -> 1, write out [20][3][2048]
    if (tid < 20) {
        const float* wr = hw3 + tid * 32;
        float bv = hb3[tid];
        float a0 = bv, a1 = bv, a2 = bv;
#pragma unroll
        for (int d = 0; d < 32; d++) {
            float w = wr[d];
            a0 = fmaf(w, sA2[tid * 32 + d], a0);
            a1 = fmaf(w, sA2[640 + tid * 32 + d], a1);
            a2 = fmaf(w, sA2[1280 + tid * 32 + d], a2);
        }
        out[(size_t)(tid * 3 + 0) * 2048 + b] = a0;
        out[(size_t)(tid * 3 + 1) * 2048 + b] = a1;
        out[(size_t)(tid * 3 + 2) * 2048 + b] = a2;
    }
}

// ---------------------------------------------------------------------------
extern "C" void kernel_launch(void* const* d_in, const int* in_sizes, int n_in,
                              void* d_out, int out_size, void* d_ws, size_t ws_size,
                              hipStream_t stream)
{
    const float* img = (const float*)d_in[0];
    const float* ew0 = (const float*)d_in[1];  const float* eb0 = (const float*)d_in[2];
    const float* ew1 = (const float*)d_in[3];  const float* eb1 = (const float*)d_in[4];
    const float* ew2 = (const float*)d_in[5];  const float* eb2 = (const float*)d_in[6];
    const float* ew3 = (const float*)d_in[7];  const float* eb3 = (const float*)d_in[8];
    const float* ew4 = (const float*)d_in[9];  const float* eb4 = (const float*)d_in[10];
    const float* ew5 = (const float*)d_in[11]; const float* eb5 = (const float*)d_in[12];
    const float* mw1 = (const float*)d_in[13]; const float* mb1 = (const float*)d_in[14];
    const float* mw2 = (const float*)d_in[15]; const float* mb2 = (const float*)d_in[16];
    const float* mw3 = (const float*)d_in[17]; const float* mb3 = (const float*)d_in[18];
    const float* wih = (const float*)d_in[19]; const float* whh = (const float*)d_in[20];
    const float* bih = (const float*)d_in[21]; const float* bhh = (const float*)d_in[22];
    const float* hw1 = (const float*)d_in[23]; const float* hb1 = (const float*)d_in[24];
    const float* hw2 = (const float*)d_in[25]; const float* hb2 = (const float*)d_in[26];
    const float* hw3 = (const float*)d_in[27]; const float* hb3 = (const float*)d_in[28];

    float* ws    = (float*)d_ws;
    float* l3out = ws;                          // [6144][512]
    float* feats = ws + (size_t)NIMG * 512;     // [6144][128]

    conv03_kernel<<<NIMG, 256, 0, stream>>>(img, ew0, eb0, ew1, eb1, ew2, eb2,
                                            ew3, eb3, l3out);
    conv45_kernel<<<NIMG / 16, 256, 0, stream>>>(l3out, ew4, eb4, ew5, eb5, feats);
    head_kernel<<<B_DIM, 64, 0, stream>>>(feats, mw1, mb1, mw2, mb2, mw3, mb3,
                                          wih, whh, bih, bhh,
                                          hw1, hb1, hw2, hb2, hw3, hb3,
                                          (float*)d_out);
}